// Round 1
// baseline (187.430 us; speedup 1.0000x reference)
//
#include <hip/hip_runtime.h>

// Problem constants (from reference setup_inputs)
#define BB 32      // batch
#define CC 16      // channels
#define TT 16384   // time
#define PP 32      // taps (N-1)
#define NNA 33     // N
#define LL 256     // chunk length
#define KK 64      // number of chunks = TT/LL

// workspace layout in floats
#define HENDT_OFF 0                      // [C][K][32(j)][32(i)]
#define YPEND_OFF (CC*KK*32*32)          // [C][K][32(b)][32(i)]
#define SSTART_OFF (2*CC*KK*32*32)       // [C][K][32(b)][32(i)]

#define LDS_STRIDE 36                    // padded row stride (floats), 16B-aligned

// ---------------------------------------------------------------------------
// Kernel A: per (c, chunk): lanes 0-31 = particular solution per batch (zero
// init), lanes 32-63 = homogeneous responses to unit initial states.
// Stores only the last-32 tails of each run.
// ---------------------------------------------------------------------------
__global__ __launch_bounds__(64)
void kA(const float* __restrict__ X, const float* __restrict__ A,
        float* __restrict__ ws) {
    __shared__ __align__(16) float lds[LL * LDS_STRIDE];
    const int bid  = blockIdx.x;          // c*KK + k
    const int c    = bid / KK;
    const int k    = bid % KK;
    const int lane = threadIdx.x;
    const int t0   = k * LL;

    // ---- stage normalized taps into LDS: lds[tau][j-1] = a[c][j][t0+tau]/a0
    const float* Ac = A + (size_t)c * NNA * TT + t0;
    float r0[LL / 64];
#pragma unroll
    for (int m = 0; m < LL / 64; ++m)
        r0[m] = 1.0f / Ac[lane + 64 * m];
#pragma unroll
    for (int j = 1; j <= PP; ++j) {
#pragma unroll
        for (int m = 0; m < LL / 64; ++m) {
            lds[(lane + 64 * m) * LDS_STRIDE + (j - 1)] =
                Ac[(size_t)j * TT + lane + 64 * m] * r0[m];
        }
    }
    __syncthreads();

    // ---- init history: hist[i] = y[i-32]
    float hist[32];
#pragma unroll
    for (int i = 0; i < 32; ++i)
        hist[i] = (lane >= 32 && (lane - 32) == i) ? 1.0f : 0.0f;

    const int  b   = lane & 31;
    const bool isx = (lane < 32);
    const float* xrow = X + ((size_t)b * CC + c) * TT + t0;

#pragma unroll 1
    for (int blk = 0; blk < LL / 32; ++blk) {
        float xv[32];
        if (isx) {
            const float4* xp = reinterpret_cast<const float4*>(xrow + blk * 32);
#pragma unroll
            for (int q = 0; q < 8; ++q) {
                float4 v = xp[q];
                xv[q * 4 + 0] = v.x; xv[q * 4 + 1] = v.y;
                xv[q * 4 + 2] = v.z; xv[q * 4 + 3] = v.w;
            }
        } else {
#pragma unroll
            for (int q = 0; q < 32; ++q) xv[q] = 0.0f;
        }
#pragma unroll
        for (int s = 0; s < 32; ++s) {
            const int tau = blk * 32 + s;
            const float4* cp =
                reinterpret_cast<const float4*>(&lds[tau * LDS_STRIDE]);
            float cf[32];
#pragma unroll
            for (int q = 0; q < 8; ++q) {
                float4 v = cp[q];
                cf[q * 4 + 0] = v.x; cf[q * 4 + 1] = v.y;
                cf[q * 4 + 2] = v.z; cf[q * 4 + 3] = v.w;
            }
            float ac[4] = {0.f, 0.f, 0.f, 0.f};
#pragma unroll
            for (int j = 2; j <= 32; ++j)
                ac[j & 3] += cf[j - 1] * hist[(s - j) & 31];
            float y = xv[s] - ((ac[0] + ac[1]) + (ac[2] + ac[3]))
                            - cf[0] * hist[(s - 1) & 31];
            hist[s & 31] = y;
        }
    }

    // ---- write tails (hist[i] = y[LL-32+i])
    float* dst = ws + (lane < 32
        ? (YPEND_OFF + ((size_t)(c * KK + k) * 32 + lane) * 32)
        : (HENDT_OFF + ((size_t)(c * KK + k) * 32 + (lane - 32)) * 32));
#pragma unroll
    for (int q = 0; q < 8; ++q) {
        float4 v = {hist[q * 4 + 0], hist[q * 4 + 1],
                    hist[q * 4 + 2], hist[q * 4 + 3]};
        reinterpret_cast<float4*>(dst)[q] = v;
    }
}

// ---------------------------------------------------------------------------
// Kernel B: sequential chunk chaining. Each half-wave handles one (b,c) pair;
// lane i holds state component s[i]. s_{k+1} = YpEnd[k] + HendT[k]^T-applied.
// ---------------------------------------------------------------------------
__global__ __launch_bounds__(64)
void kB(float* __restrict__ ws) {
    const int lane = threadIdx.x;
    const int i    = lane & 31;
    const int q    = blockIdx.x * 2 + (lane >> 5);  // pair index = c*32 + b
    const int c    = q >> 5;
    const int b    = q & 31;

    const float* H  = ws + HENDT_OFF;
    const float* Yp = ws + YPEND_OFF;
    float*       Ss = ws + SSTART_OFF;

    float sv = 0.0f;
    for (int k = 0; k < KK; ++k) {
        const size_t base = (size_t)(c * KK + k) * 32;
        Ss[(base + b) * 32 + i] = sv;            // state at chunk start
        const float yp = Yp[(base + b) * 32 + i];
        float h[32];
#pragma unroll
        for (int j = 0; j < 32; ++j)
            h[j] = H[(base + j) * 32 + i];
        float ac[4] = {0.f, 0.f, 0.f, 0.f};
#pragma unroll
        for (int j = 0; j < 32; ++j) {
            const float sb = __shfl(sv, (lane & 32) + j, 64);
            ac[j & 3] += h[j] * sb;
        }
        sv = yp + ((ac[0] + ac[1]) + (ac[2] + ac[3]));
    }
}

// ---------------------------------------------------------------------------
// Kernel C: re-run the exact recurrence per chunk with the correct initial
// state, writing y. Lanes 0-31 = batches; lanes 32-63 idle (compute zeros).
// ---------------------------------------------------------------------------
__global__ __launch_bounds__(64)
void kC(const float* __restrict__ X, const float* __restrict__ A,
        const float* __restrict__ ws, float* __restrict__ Y) {
    __shared__ __align__(16) float lds[LL * LDS_STRIDE];
    const int bid  = blockIdx.x;          // c*KK + k
    const int c    = bid / KK;
    const int k    = bid % KK;
    const int lane = threadIdx.x;
    const int t0   = k * LL;

    const float* Ac = A + (size_t)c * NNA * TT + t0;
    float r0[LL / 64];
#pragma unroll
    for (int m = 0; m < LL / 64; ++m)
        r0[m] = 1.0f / Ac[lane + 64 * m];
#pragma unroll
    for (int j = 1; j <= PP; ++j) {
#pragma unroll
        for (int m = 0; m < LL / 64; ++m) {
            lds[(lane + 64 * m) * LDS_STRIDE + (j - 1)] =
                Ac[(size_t)j * TT + lane + 64 * m] * r0[m];
        }
    }
    __syncthreads();

    const int  b   = lane & 31;
    const bool act = (lane < 32);

    float hist[32];
    if (act) {
        const float4* sp = reinterpret_cast<const float4*>(
            ws + SSTART_OFF + ((size_t)(c * KK + k) * 32 + b) * 32);
#pragma unroll
        for (int qq = 0; qq < 8; ++qq) {
            float4 v = sp[qq];
            hist[qq * 4 + 0] = v.x; hist[qq * 4 + 1] = v.y;
            hist[qq * 4 + 2] = v.z; hist[qq * 4 + 3] = v.w;
        }
    } else {
#pragma unroll
        for (int i = 0; i < 32; ++i) hist[i] = 0.0f;
    }

    const float* xrow = X + ((size_t)b * CC + c) * TT + t0;
    float*       yrow = Y + ((size_t)b * CC + c) * TT + t0;

#pragma unroll 1
    for (int blk = 0; blk < LL / 32; ++blk) {
        float xv[32];
        if (act) {
            const float4* xp = reinterpret_cast<const float4*>(xrow + blk * 32);
#pragma unroll
            for (int q = 0; q < 8; ++q) {
                float4 v = xp[q];
                xv[q * 4 + 0] = v.x; xv[q * 4 + 1] = v.y;
                xv[q * 4 + 2] = v.z; xv[q * 4 + 3] = v.w;
            }
        } else {
#pragma unroll
            for (int q = 0; q < 32; ++q) xv[q] = 0.0f;
        }
#pragma unroll
        for (int s = 0; s < 32; ++s) {
            const int tau = blk * 32 + s;
            const float4* cp =
                reinterpret_cast<const float4*>(&lds[tau * LDS_STRIDE]);
            float cf[32];
#pragma unroll
            for (int q = 0; q < 8; ++q) {
                float4 v = cp[q];
                cf[q * 4 + 0] = v.x; cf[q * 4 + 1] = v.y;
                cf[q * 4 + 2] = v.z; cf[q * 4 + 3] = v.w;
            }
            float ac[4] = {0.f, 0.f, 0.f, 0.f};
#pragma unroll
            for (int j = 2; j <= 32; ++j)
                ac[j & 3] += cf[j - 1] * hist[(s - j) & 31];
            float y = xv[s] - ((ac[0] + ac[1]) + (ac[2] + ac[3]))
                            - cf[0] * hist[(s - 1) & 31];
            hist[s & 31] = y;
            xv[s] = y;   // reuse xv as output buffer
        }
        if (act) {
            float4* yp4 = reinterpret_cast<float4*>(yrow + blk * 32);
#pragma unroll
            for (int q = 0; q < 8; ++q) {
                float4 v = {xv[q * 4 + 0], xv[q * 4 + 1],
                            xv[q * 4 + 2], xv[q * 4 + 3]};
                yp4[q] = v;
            }
        }
    }
}

extern "C" void kernel_launch(void* const* d_in, const int* in_sizes, int n_in,
                              void* d_out, int out_size, void* d_ws, size_t ws_size,
                              hipStream_t stream) {
    const float* X = (const float*)d_in[0];   // (B,C,T)
    const float* A = (const float*)d_in[1];   // (C,N,T)
    float* Y  = (float*)d_out;                // (B,C,T)
    float* ws = (float*)d_ws;                 // needs 12 MB

    kA<<<CC * KK, 64, 0, stream>>>(X, A, ws);
    kB<<<(BB * CC) / 2, 64, 0, stream>>>(ws);
    kC<<<CC * KK, 64, 0, stream>>>(X, A, ws, Y);
}